// Round 8
// baseline (391.188 us; speedup 1.0000x reference)
//
#include <hip/hip_runtime.h>

// AdEx neuron simulation: T=500 steps, N=100000 neurons. One wave per 64 neurons.
// R11 = R9 (LDS-staged input) with ONE change: plain stores, not nontemporal.
// Evidence chain:
//  - R10 (reg ring + plain stores): adex dropped 130 -> <119us (fell out of
//    rocprof top-5) => store-retire latency WAS on the critical path.
//  - Residual binder in R10: reg ring caps in-flight reads at 4.8MB chip-wide
//    (R8: compiler refuses depth >~12) -> ~1.7 TB/s read.
//  - R9 (LDS staging, 8KB/wave in flight) was tested with NT stores: the
//    32 prev-tile nt stores pinned the in-order vmcnt queue (63-op issue cap)
//    -> per-tile multi-us stall -> 177us. Plain stores retire at L2-accept,
//    so the per-tile vmcnt(32) drain becomes ~hundreds of cycles.
//  - fillBufferAligned in R10's profile: 6.64 TB/s writes -> ceiling is real.
// Structure: 32-step tiles (8KB) double-buffered in two __shared__ arrays,
// global_load_lds width 16 (8 DMA/tile) issued at tile start (overlaps prev
// tile compute); consume = ds_read_b32 prefetched 4 ahead (lgkmcnt, free of
// the store stream); one s_waitcnt vmcnt(32) per tile (in-order retire =>
// drains the 8 stagings, leaves newest 32 stores outstanding); 1-wave blocks,
// no barriers. LDS 16KB/block, 6.1 blocks/CU.
// Per-neuron math bit-identical to R3 -> absmax must stay 4.8828e-4.
// Numerics: contract(off), left-to-right order, precise expf.

#define TS 32   // timesteps per LDS tile

__device__ __forceinline__ void stage16(const void* g, void* l) {
    // DMA 16B/lane global->LDS; LDS dest = uniform base + lane*16 (m104).
    __builtin_amdgcn_global_load_lds(
        (const __attribute__((address_space(1))) void*)g,
        (__attribute__((address_space(3))) void*)l, 16, 0, 0);
}
__device__ __forceinline__ void stage4(const void* g, void* l) {
    __builtin_amdgcn_global_load_lds(
        (const __attribute__((address_space(1))) void*)g,
        (__attribute__((address_space(3))) void*)l, 4, 0, 0);
}

template <bool FULL>
__device__ __forceinline__ void run_sim(
    const float* __restrict__ I,
    const float* __restrict__ v0,
    const float* __restrict__ c0,
    const int*   __restrict__ ref0,
    float*       __restrict__ out,
    int N, int T, float* bufA, float* bufB)
{
#pragma clang fp contract(off)
    const float EL       = (float)(-70.6e-3);
    const float VT       = (float)(-50.4e-3);
    const float DELTAT   = (float)(2e-3);
    const float R_DELTAT = (float)(1.0 / (double)((float)(2e-3)));  // fl(1/d)
    const float NEG_GL   = (float)(-30e-9);
    const float GLDT     = (float)(30e-9 * 2e-3);        // GL*DELTAT
    const float DT_CM    = (float)(1e-3 / 281e-12);      // DT/CM
    const float DT_TAUW  = (float)(1e-3 / 144e-3);       // DT/TAUW
    const float Af       = (float)(4e-9);
    const float Bf       = (float)(0.0805e-9);
    const int   REF_STEPS = 2;

    const int lane   = threadIdx.x;        // 64-thread block = 1 wave
    const int n_base = blockIdx.x * 64;
    const int n      = n_base + lane;
    const bool active = FULL || (n < N);
    const int  nld    = FULL ? n : (n < N ? n : N - 1);

    float v  = v0[nld];
    float c  = c0[nld];
    int   rf = ref0[nld];

    const unsigned stride_b = (unsigned)N * 4u;
    const char* Ic = (const char*)I;
    char*       oc = (char*)out;

    // One simulation step. Same op order as R3 (bit-identical).
    auto step = [&](float It) -> float {
        bool  in_ref = rf > 0;
        float v_eff  = in_ref ? EL : v;

        float x   = v_eff - VT;
        float y0  = x * R_DELTAT;
        float e   = fmaf(-DELTAT, y0, x);
        float arg = fmaf(e, R_DELTAT, y0);
        arg = fminf(arg, 15.0f);
        float exp_term = GLDT * expf(arg);

        float acc = NEG_GL * (v_eff - EL);
        acc = acc + exp_term;
        acc = acc - c;
        acc = acc + It;
        float dv = DT_CM * acc;

        float v_new = in_ref ? EL : (v_eff + dv);
        float c_new = c + DT_TAUW * ((Af * (v_eff - EL)) - c);

        bool  spike = v_new >= VT;
        float v_out = spike ? EL : v_new;

        c  = spike ? (c_new + Bf) : c_new;
        rf = spike ? REF_STEPS : (in_ref ? rf - 1 : 0);
        v  = v_out;
        return v_out;
    };

    // 16B-staging per-lane source: lane l covers row (l>>4), col bytes
    // n_base*4 + (l&15)*16. Column part is lane-constant -> clamp once.
    int col16 = n_base * 4 + (lane & 15) * 16;
    if (!FULL) { int mx = N * 4 - 16; col16 = col16 < mx ? col16 : mx; }
    const char* gst = Ic + (size_t)(lane >> 4) * stride_b + (size_t)col16;

    int col4 = n * 4;
    if (!FULL) { int mx = N * 4 - 4; col4 = col4 < mx ? col4 : mx; }

    unsigned off = (unsigned)n * 4u;   // store byte offset, walks t

    const int nt = (T + TS - 1) / TS;

    // Stage tile k (rows k*TS .. min(k*TS+TS,T)-1) into sb. 4 rows per 16B
    // DMA instr; tail rows (<4) staged per-row with 4B DMA.
    auto stage_tile = [&](int k, float* sb) {
        int t0   = k * TS;
        int rows = T - t0; if (rows > TS) rows = TS;
        int full = rows >> 2;
        for (int i = 0; i < full; ++i) {
            stage16(gst, sb + i * 256);          // 256 floats = 1024B = 4 rows
            gst += 4 * (size_t)stride_b;
        }
        int rem = rows & 3;
        if (rem) {
            const char* g4 = Ic + (size_t)(t0 + (full << 2)) * stride_b + (size_t)col4;
            float* lb = sb + (full << 2) * 64;
            for (int r = 0; r < rem; ++r) {
                stage4(g4, lb);
                g4 += stride_b; lb += 64;
            }
        }
    };

    // One tile: stage next tile into sb, compute this tile from rb.
    auto tile_body = [&](int k, const float* rb, float* sb) {
        if (k + 1 < nt) stage_tile(k + 1, sb);

        int rows = T - k * TS; if (rows > TS) rows = TS;

        float ring[4];
#pragma unroll
        for (int i = 0; i < 4; ++i)
            if (i < rows) ring[i] = rb[i * 64 + lane];

#pragma unroll
        for (int r = 0; r < TS; ++r) {
            if (r < rows) {
                float It = ring[r & 3];
                if (r + 4 < rows) ring[r & 3] = rb[(r + 4) * 64 + lane];
                float v_out = step(It);
                if (active)
                    *(float*)(oc + off) = v_out;   // plain store: L2-accept retire
                off += stride_b;
            }
        }
        // Retire this body's stagings (issued before its 32 stores) while
        // leaving the 32 newest stores outstanding. In-order vmcnt retire:
        // the 8 oldest (stagings) drain first -> LDS guaranteed landed for
        // the next body's ds_reads; stores drain cheaply behind L2.
        asm volatile("s_waitcnt vmcnt(32)" ::: "memory");
    };

    // Prologue: stage tile 0 and drain (only stagings outstanding).
    stage_tile(0, bufA);
    asm volatile("s_waitcnt vmcnt(0)" ::: "memory");

    // 2x-unrolled tile loop -> static LDS buffer names (clean aliasing).
    for (int k = 0; k < nt; k += 2) {
        tile_body(k, bufA, bufB);
        if (k + 1 < nt) tile_body(k + 1, bufB, bufA);
    }
}

__global__ __launch_bounds__(64) void adex_kernel(
    const float* __restrict__ I,
    const float* __restrict__ v0,
    const float* __restrict__ c0,
    const int*   __restrict__ ref0,
    float*       __restrict__ out,
    int N, int T)
{
    __shared__ float bufA[TS * 64];   // 8 KB
    __shared__ float bufB[TS * 64];   // 8 KB

    if (blockIdx.x * 64 + 64 <= (unsigned)N) {
        run_sim<true >(I, v0, c0, ref0, out, N, T, bufA, bufB);
    } else {
        run_sim<false>(I, v0, c0, ref0, out, N, T, bufA, bufB);
    }
}

extern "C" void kernel_launch(void* const* d_in, const int* in_sizes, int n_in,
                              void* d_out, int out_size, void* d_ws, size_t ws_size,
                              hipStream_t stream) {
    const float* I    = (const float*)d_in[0];
    const float* v0   = (const float*)d_in[1];
    const float* c0   = (const float*)d_in[2];
    const int*   ref0 = (const int*)d_in[3];
    float*       out  = (float*)d_out;

    int N = in_sizes[1];            // 100000
    int T = in_sizes[0] / N;        // 500

    dim3 block(64);
    dim3 grid((N + 63) / 64);       // 1563 one-wave blocks -> 6-7 waves/CU
    adex_kernel<<<grid, block, 0, stream>>>(I, v0, c0, ref0, out, N, T);
}

// Round 9
// 383.598 us; speedup vs baseline: 1.0198x; 1.0198x over previous
//
#include <hip/hip_runtime.h>

// AdEx neuron simulation: T=500 steps, N=100000 neurons. One thread per neuron.
// R12: forced-depth register double-buffer (batch issue + sched_barrier).
// Evidence chain:
//  - R10 (rolling ring DEPTH12 + plain stores) ~115-119us = best. Little's law:
//    4.8MB in-flight reads @ 2.8us queued latency -> 560 cyc/step exact fit.
//    Load-MLP-capped at the ring depth the compiler tolerates.
//  - R8 (DEPTH 24): VGPR only +8 -> compiler SINKS rolling-ring loads back
//    toward uses; source-level depth is ignored.
//  - R11 (LDS staging + plain stores) 165us: staging VALU overhead dominates;
//    dead end. Registers, not LDS.
//  - fill kernels: 6.6 TB/s -> HBM has 4x headroom over R10's 1.7 TB/s read.
// Fix: per 32-step tile, issue ALL 32 next-tile loads back-to-back, then
// __builtin_amdgcn_sched_barrier(0) (nothing may cross), then compute the
// current tile from the other register buffer. Compiler cannot sink the
// batch -> true depth 32-64, in-flight ~12.8MB chip-wide.
// vmcnt: 32 loads + 32 plain stores outstanding ~64; consume waits clamp at
// vmcnt(63) -> waits ~1 op extra, negligible. VGPR ~100 (irrelevant at 1.5
// waves/SIMD). Plain stores (L2-accept retire, R10's win) kept.
// Per-neuron math bit-identical to R3 -> absmax must stay 4.8828e-4.
// Numerics: contract(off), left-to-right order, precise expf.

#define TS 32   // timesteps per register tile

__global__ __launch_bounds__(64) void adex_kernel(
    const float* __restrict__ I,
    const float* __restrict__ v0,
    const float* __restrict__ c0,
    const int*   __restrict__ ref0,
    float*       __restrict__ out,
    int N, int T)
{
#pragma clang fp contract(off)
    const float EL       = (float)(-70.6e-3);
    const float VT       = (float)(-50.4e-3);
    const float DELTAT   = (float)(2e-3);
    const float R_DELTAT = (float)(1.0 / (double)((float)(2e-3)));  // fl(1/d)
    const float NEG_GL   = (float)(-30e-9);
    const float GLDT     = (float)(30e-9 * 2e-3);        // GL*DELTAT
    const float DT_CM    = (float)(1e-3 / 281e-12);      // DT/CM
    const float DT_TAUW  = (float)(1e-3 / 144e-3);       // DT/TAUW
    const float Af       = (float)(4e-9);
    const float Bf       = (float)(0.0805e-9);
    const int   REF_STEPS = 2;

    int n = blockIdx.x * blockDim.x + threadIdx.x;
    if (n >= N) return;

    float v  = v0[n];
    float c  = c0[n];
    int   rf = ref0[n];

    const unsigned stride_b = (unsigned)N * 4u;
    const char* Icp = (const char*)I   + (size_t)n * 4u;
    char*       ocp = (char*)out       + (size_t)n * 4u;
    unsigned lo = 0;   // load  byte offset (walks t)
    unsigned so = 0;   // store byte offset (walks t)

    // One simulation step. Updates v, c, rf; returns v_out. Same op order as R3.
    auto step = [&](float It) -> float {
        bool  in_ref = rf > 0;
        float v_eff  = in_ref ? EL : v;

        // arg = (v_eff - VT) / DELTAT  — Newton/fma faithful division
        float x   = v_eff - VT;
        float y0  = x * R_DELTAT;
        float e   = fmaf(-DELTAT, y0, x);
        float arg = fmaf(e, R_DELTAT, y0);
        arg = fminf(arg, 15.0f);
        float exp_term = GLDT * expf(arg);

        float acc = NEG_GL * (v_eff - EL);
        acc = acc + exp_term;
        acc = acc - c;
        acc = acc + It;
        float dv = DT_CM * acc;

        float v_new = in_ref ? EL : (v_eff + dv);
        float c_new = c + DT_TAUW * ((Af * (v_eff - EL)) - c);

        bool  spike = v_new >= VT;
        float v_out = spike ? EL : v_new;

        c  = spike ? (c_new + Bf) : c_new;
        rf = spike ? REF_STEPS : (in_ref ? rf - 1 : 0);
        v  = v_out;
        return v_out;
    };

    float A[TS], B[TS];   // two register tile buffers, statically indexed only

    if (T >= TS) {
        int t_done = 0;   // steps computed
        int l_done = TS;  // steps loaded

        // Prologue: batch-load tile 0 into A, pin with sched_barrier.
#pragma unroll
        for (int j = 0; j < TS; ++j) { A[j] = *(const float*)(Icp + lo); lo += stride_b; }
        __builtin_amdgcn_sched_barrier(0);

        for (;;) {
            // ---- phase A: batch-prefetch into B, compute tile from A ----
            {
                int nl = T - l_done; if (nl > TS) nl = TS;   // uniform across wave
#pragma unroll
                for (int j = 0; j < TS; ++j)
                    if (j < nl) { B[j] = *(const float*)(Icp + lo); lo += stride_b; }
                __builtin_amdgcn_sched_barrier(0);
                l_done += nl;

                int cnt = T - t_done; if (cnt > TS) cnt = TS;
#pragma unroll
                for (int j = 0; j < TS; ++j)
                    if (j < cnt) {
                        float vo = step(A[j]);
                        *(float*)(ocp + so) = vo;   // plain store: L2-accept retire
                        so += stride_b;
                    }
                t_done += cnt;
                if (t_done >= T) break;
            }
            // ---- phase B: batch-prefetch into A, compute tile from B ----
            {
                int nl = T - l_done; if (nl > TS) nl = TS;
#pragma unroll
                for (int j = 0; j < TS; ++j)
                    if (j < nl) { A[j] = *(const float*)(Icp + lo); lo += stride_b; }
                __builtin_amdgcn_sched_barrier(0);
                l_done += nl;

                int cnt = T - t_done; if (cnt > TS) cnt = TS;
#pragma unroll
                for (int j = 0; j < TS; ++j)
                    if (j < cnt) {
                        float vo = step(B[j]);
                        *(float*)(ocp + so) = vo;
                        so += stride_b;
                    }
                t_done += cnt;
                if (t_done >= T) break;
            }
        }
    } else {
        // Tiny-T fallback (not hit at T=500): simple unpipelined loop.
        for (int tt = 0; tt < T; ++tt) {
            float It = *(const float*)(Icp + lo); lo += stride_b;
            float vo = step(It);
            *(float*)(ocp + so) = vo; so += stride_b;
        }
    }
}

extern "C" void kernel_launch(void* const* d_in, const int* in_sizes, int n_in,
                              void* d_out, int out_size, void* d_ws, size_t ws_size,
                              hipStream_t stream) {
    const float* I    = (const float*)d_in[0];
    const float* v0   = (const float*)d_in[1];
    const float* c0   = (const float*)d_in[2];
    const int*   ref0 = (const int*)d_in[3];
    float*       out  = (float*)d_out;

    int N = in_sizes[1];            // 100000
    int T = in_sizes[0] / N;        // 500

    dim3 block(64);
    dim3 grid((N + 63) / 64);       // 1563 one-wave blocks -> 6-7 waves/CU, even
    adex_kernel<<<grid, block, 0, stream>>>(I, v0, c0, ref0, out, N, T);
}